// Round 6
// baseline (304.000 us; speedup 1.0000x reference)
//
#include <hip/hip_runtime.h>

// Problem constants
#define BATCH 32
#define CCH 3
#define HW_TEX (512 * 512)
#define N_TEX (HW_TEX * CCH)          // 786432 per-sample flat texture (channels-last)
#define OH 128
#define OW 64
#define P_OUT (OH * OW)               // 8192
#define M_OUT (P_OUT * CCH)           // 24576 rows per sample (channels-last)
#define NNZ 98304
#define OUT_ELEMS (BATCH * M_OUT)     // 786432

// R12 architecture: single-pass global-atomic scatter.
// Evidence trail: R6-R10 identical at 72us across 4 codegen rewrites; R11
// (2x waves, +41% line-requests) got SLOWER -> per-CU outstanding-miss pool
// (MSHR) saturated at 16 waves; time scales with total L1-miss LINES, not
// concurrency. The chunked-LDS scheme reads every index triple NCH times and
// round-trips 25 MB of partials. This pass touches each nnz ONCE and uses
// fire-and-forget global atomicAdd (write path, no MSHR wait):
//   lines/CU ~14.5k vs ~23.8k -> predicted scan ~45us, reduce pass deleted.
// XCD phasing kept: per round, XCD k scans sample s=rnd*8+k (x stays L2-hot).
#define SC_TB 1024
#define NROUND 4

__global__ __launch_bounds__(SC_TB) void scatter_kernel(
    const float* __restrict__ x,
    const int*   __restrict__ rows,
    const int*   __restrict__ cols,
    const float* __restrict__ vals,
    float* __restrict__ out) {
    const int blk  = blockIdx.x;      // 256 = 32 blocks x 8 XCDs
    const int xcd  = blk & 7;
    const int slot = blk >> 3;        // 0..31
    const int t    = threadIdx.x;
    const int base = slot * SC_TB + t;        // 0..32767 within sample

    for (int rnd = 0; rnd < NROUND; ++rnd) {
        const int s = rnd * 8 + xcd;
        const size_t ib = (size_t)s * NNZ;
        const float* xs = x + (size_t)s * N_TEX;
        float* os = out + (size_t)s * M_OUT;

        // 3 nnz per thread at stride 32768: fully coalesced scalar loads
        // (wave = 64 consecutive lanes = 4 lines per load instruction).
        int   r0 = rows[ib + base];
        int   r1 = rows[ib + base + 32768];
        int   r2 = rows[ib + base + 65536];
        int   c0 = cols[ib + base];
        int   c1 = cols[ib + base + 32768];
        int   c2 = cols[ib + base + 65536];
        float v0 = vals[ib + base];
        float v1 = vals[ib + base + 32768];
        float v2 = vals[ib + base + 65536];

        // gathers (the only latency-bound lines besides the index streams)
        float x0 = xs[(c0 % CCH) * HW_TEX + c0 / CCH];
        float x1 = xs[(c1 % CCH) * HW_TEX + c1 / CCH];
        float x2 = xs[(c2 % CCH) * HW_TEX + c2 / CCH];

        // CHW-transformed scatter, fire-and-forget device atomics
        atomicAdd(&os[(r0 % CCH) * P_OUT + r0 / CCH], v0 * x0);
        atomicAdd(&os[(r1 % CCH) * P_OUT + r1 / CCH], v1 * x1);
        atomicAdd(&os[(r2 % CCH) * P_OUT + r2 / CCH], v2 * x2);
    }
}

// ---------- init: zero result region + copy mask ----------------------------
__global__ __launch_bounds__(256) void init_out_kernel(
    const float* __restrict__ mask,
    float* __restrict__ out) {
    int tid = blockIdx.x * 256 + threadIdx.x;   // over OUT_ELEMS/4
    if (tid >= OUT_ELEMS / 4) return;
    reinterpret_cast<float4*>(out)[tid] = make_float4(0.f, 0.f, 0.f, 0.f);
    reinterpret_cast<float4*>(out + OUT_ELEMS)[tid] =
        reinterpret_cast<const float4*>(mask)[tid];
}

extern "C" void kernel_launch(void* const* d_in, const int* in_sizes, int n_in,
                              void* d_out, int out_size, void* d_ws, size_t ws_size,
                              hipStream_t stream) {
    const float* x    = (const float*)d_in[0];
    const int*   rows = (const int*)  d_in[1];
    const int*   cols = (const int*)  d_in[2];
    const float* vals = (const float*)d_in[3];
    const float* mask = (const float*)d_in[4];
    float* out = (float*)d_out;

    int igrid = (OUT_ELEMS / 4 + 255) / 256;   // 768
    init_out_kernel<<<igrid, 256, 0, stream>>>(mask, out);
    scatter_kernel<<<256, SC_TB, 0, stream>>>(x, rows, cols, vals, out);
}

// Round 7
// 223.023 us; speedup vs baseline: 1.3631x; 1.3631x over previous
//
#include <hip/hip_runtime.h>

// Problem constants
#define BATCH 32
#define CCH 3
#define HW_TEX (512 * 512)
#define N_TEX (HW_TEX * CCH)          // 786432 per-sample flat texture (channels-last)
#define OH 128
#define OW 64
#define P_OUT (OH * OW)               // 8192
#define M_OUT (P_OUT * CCH)           // 24576 rows per sample (channels-last)
#define NNZ 98304
#define OUT_ELEMS (BATCH * M_OUT)     // 786432

// Geometry (R6-proven): grid 256 (1 block/CU), per XCD 32 slots = 4 chunks x 8 segs.
#define NCH 4                          // row chunks per sample
#define RPCH (M_OUT / NCH)             // 6144 rows -> 24 KB LDS acc
#define NE 8                           // nnz segments
#define SEGE (NNZ / NE)                // 12288 nnz per block-round
#define TB 1024
#define NROUND 4                       // sample phases per XCD
#define TILE 3072                      // nnz per staged tile (4 tiles/round)
#define EPT 3                          // elems per thread per tile

#define WS_NEED ((size_t)BATCH * NCH * NE * RPCH * 4)   // 25.17 MB

// direct global->LDS DMA (side-effecting intrinsic: compiler cannot re-sink
// or serialize it -- the scheduling property R7-R10 failed to get from the
// register allocator). vmcnt tracks completion.
__device__ __forceinline__ void gld_lds16(const void* g, void* l) {
    __builtin_amdgcn_global_load_lds(
        (const __attribute__((address_space(1))) void*)g,
        (__attribute__((address_space(3))) void*)l, 16, 0, 0);
}
__device__ __forceinline__ void gld_lds4(const void* g, void* l) {
    __builtin_amdgcn_global_load_lds(
        (const __attribute__((address_space(1))) void*)g,
        (__attribute__((address_space(3))) void*)l, 4, 0, 0);
}

// ---------- scan: chunk-specialized, ALL-DMA (global_load_lds) version ------
// R13 theory: scan is outstanding-miss-pool bound on the VGPR-return path
// (~0.13 lines/cy/CU, invariant across R6-R11). Route every global read
// through the direct-to-LDS DMA path instead: indices staged per 3072-nnz
// tile, gathers issued per-lane into an LDS slot and consumed from LDS.
// If the DMA queue is deeper than the MSHR pool -> scan ~40-55us; if it
// shares the pool -> unchanged (definitive null).
__global__ __launch_bounds__(TB) void scan_pred8_kernel(
    const float* __restrict__ x,
    const int*   __restrict__ rows,
    const int*   __restrict__ cols,
    const float* __restrict__ vals,
    float* __restrict__ partial) {
    __shared__ __align__(16) float acc[RPCH];        // 24 KB
    __shared__ __align__(16) int   s_idx[3][TILE];   // 36 KB (rows,cols,vals)
    __shared__ __align__(16) float s_gath[TILE];     // 12 KB

    const int blk  = blockIdx.x;
    const int xcd  = blk & 7;
    const int slot = blk >> 3;
    const int c    = slot & (NCH - 1);
    const int e    = slot >> 2;
    const int t    = threadIdx.x;
    const int lane = t & 63;
    const int w    = t >> 6;                 // wave id, 16 waves
    const int rbase = c * RPCH;

    for (int rnd = 0; rnd < NROUND; ++rnd) {
        const int s = rnd * 8 + xcd;

        // zero 24 KB acc
        float2* acc2 = reinterpret_cast<float2*>(acc);
#pragma unroll
        for (int j = 0; j < RPCH / 2 / TB; ++j)
            acc2[t + j * TB] = make_float2(0.f, 0.f);
        __syncthreads();

        const size_t off = (size_t)s * NNZ + (size_t)e * SEGE;
        const float* xs = x + (size_t)s * N_TEX;
        const int* gsrc[3] = { rows + off, cols + off,
                               reinterpret_cast<const int*>(vals + off) };

        for (int tt = 0; tt < SEGE / TILE; ++tt) {
            const int toff = tt * TILE;

            // ---- A: DMA-stage the index tile (36 KB = 36 x 1KB chunks).
            // chunk q: array q/12, sub-chunk q%12; each wave-inst moves
            // 64 lanes x 16B = 1 KB.  Waves stripe q = w, w+16, w+32.
            for (int q = w; q < 36; q += 16) {
                const int arr = q / 12, sub = q % 12;
                gld_lds16(gsrc[arr] + toff + sub * 256 + lane * 4,
                          &s_idx[arr][sub * 256]);
            }
            __syncthreads();   // implicit vmcnt(0) drain + barrier: tile visible

            // ---- C: issue predicated gather-DMAs (same request count as R6).
            // Dest base is wave-uniform; HW writes lane slot base+lane*4.
            // Exec-masked lanes write nothing (their slot is never read).
#pragma unroll
            for (int k = 0; k < EPT; ++k) {
                const int n = w * (EPT * 64) + k * 64 + lane;
                int rI = s_idx[0][n];
                int cI = s_idx[1][n];
                unsigned l = (unsigned)(rI - rbase);
                if (l < (unsigned)RPCH) {
                    int gi = (cI % CCH) * HW_TEX + cI / CCH;
                    gld_lds4(xs + gi, &s_gath[w * (EPT * 64) + k * 64]);
                }
            }
            // drain own wave's gather-DMAs; fence ds_reads below it (rule 18)
            asm volatile("s_waitcnt vmcnt(0)" ::: "memory");
            __builtin_amdgcn_sched_barrier(0);

            // ---- E: consume from LDS, accumulate
#pragma unroll
            for (int k = 0; k < EPT; ++k) {
                const int n = w * (EPT * 64) + k * 64 + lane;
                unsigned l = (unsigned)(s_idx[0][n] - rbase);
                if (l < (unsigned)RPCH) {
                    float vv = __int_as_float(s_idx[2][n]);
                    atomicAdd(&acc[l], vv * s_gath[n]);
                }
            }
            __syncthreads();   // protect s_idx/s_gath before next tile's DMA
        }

        // dump 24 KB partial, coalesced float2
        float2* pp = reinterpret_cast<float2*>(
            partial + (((size_t)s * NCH + c) * NE + e) * RPCH);
#pragma unroll
        for (int j = 0; j < RPCH / 2 / TB; ++j)
            pp[t + j * TB] = acc2[t + j * TB];
        __syncthreads();
    }
}

// ---------- reduce: sum NE partials per (s,chunk,row), CHW transform, mask --
__global__ __launch_bounds__(256) void reduce_chunk_kernel(
    const float* __restrict__ partial,
    const float* __restrict__ mask,
    float* __restrict__ out) {
    int tid = blockIdx.x * 256 + threadIdx.x;       // over OUT_ELEMS/4
    if (tid >= OUT_ELEMS / 4) return;
    int s    = tid / (M_OUT / 4);
    int rcl4 = (tid % (M_OUT / 4)) * 4;             // 4 consecutive channels-last rows
    int c    = rcl4 / RPCH;                         // chunk (RPCH % 4 == 0)
    int lr4  = rcl4 % RPCH;

    const float4* pp = reinterpret_cast<const float4*>(
        partial + (((size_t)s * NCH + c) * NE) * RPCH + lr4);
    float4 sum = make_float4(0.f, 0.f, 0.f, 0.f);
#pragma unroll
    for (int e = 0; e < NE; ++e) {
        float4 p = pp[(size_t)e * (RPCH / 4)];
        sum.x += p.x; sum.y += p.y; sum.z += p.z; sum.w += p.w;
    }
    float* ob = out + (size_t)s * M_OUT;
    ob[(rcl4 + 0) % CCH * P_OUT + (rcl4 + 0) / CCH] = sum.x;
    ob[(rcl4 + 1) % CCH * P_OUT + (rcl4 + 1) / CCH] = sum.y;
    ob[(rcl4 + 2) % CCH * P_OUT + (rcl4 + 2) / CCH] = sum.z;
    ob[(rcl4 + 3) % CCH * P_OUT + (rcl4 + 3) / CCH] = sum.w;
    reinterpret_cast<float4*>(out + OUT_ELEMS)[tid] =
        reinterpret_cast<const float4*>(mask)[tid];
}

// ---------- fallback (R2): no workspace needed ------------------------------
#define CHUNKS 8
#define RPC (M_OUT / CHUNKS)
#define BLOCK 1024
__global__ __launch_bounds__(BLOCK) void spmm_chunk_kernel(
    const float* __restrict__ x,
    const int*   __restrict__ rows,
    const int*   __restrict__ cols,
    const float* __restrict__ vals,
    const float* __restrict__ mask,
    float* __restrict__ out) {
    __shared__ float acc[RPC];
    const int blk = blockIdx.x;
    const int s   = blk / CHUNKS;
    const int c   = blk % CHUNKS;
    const int t   = threadIdx.x;
    const int rbase = c * RPC;
#pragma unroll
    for (int j = 0; j < RPC / BLOCK; ++j) acc[t + j * BLOCK] = 0.0f;
    __syncthreads();
    const int*   rs = rows + (size_t)s * NNZ;
    const int*   cs = cols + (size_t)s * NNZ;
    const float* vs = vals + (size_t)s * NNZ;
    const float* xs = x    + (size_t)s * N_TEX;
#pragma unroll 4
    for (int i = t; i < NNZ; i += BLOCK) {
        int r = rs[i];
        unsigned lr = (unsigned)(r - rbase);
        if (lr < (unsigned)RPC) {
            int   col = cs[i];
            float v   = vs[i];
            atomicAdd(&acc[lr], v * xs[(col % CCH) * HW_TEX + col / CCH]);
        }
    }
    __syncthreads();
    const size_t outbase = (size_t)s * M_OUT;
#pragma unroll
    for (int ch = 0; ch < CCH; ++ch)
        out[outbase + (size_t)ch * P_OUT + c * (P_OUT / CHUNKS) + t] = acc[t * CCH + ch];
    {
        float* mout = out + OUT_ELEMS;
        const int base = blk * RPC;
#pragma unroll
        for (int j = 0; j < RPC / BLOCK; ++j)
            mout[base + j * BLOCK + t] = mask[base + j * BLOCK + t];
    }
}

extern "C" void kernel_launch(void* const* d_in, const int* in_sizes, int n_in,
                              void* d_out, int out_size, void* d_ws, size_t ws_size,
                              hipStream_t stream) {
    const float* x    = (const float*)d_in[0];
    const int*   rows = (const int*)  d_in[1];
    const int*   cols = (const int*)  d_in[2];
    const float* vals = (const float*)d_in[3];
    const float* mask = (const float*)d_in[4];
    float* out = (float*)d_out;
    int rgrid = (OUT_ELEMS / 4 + 255) / 256;   // 768

    if (ws_size >= WS_NEED) {
        float* partial = (float*)d_ws;
        scan_pred8_kernel<<<256, TB, 0, stream>>>(x, rows, cols, vals, partial);
        reduce_chunk_kernel<<<rgrid, 256, 0, stream>>>(partial, mask, out);
    } else {
        spmm_chunk_kernel<<<BATCH * CHUNKS, BLOCK, 0, stream>>>(x, rows, cols, vals, mask, out);
    }
}

// Round 8
// 212.225 us; speedup vs baseline: 1.4324x; 1.0509x over previous
//
#include <hip/hip_runtime.h>

// Problem constants
#define BATCH 32
#define CCH 3
#define HW_TEX (512 * 512)
#define N_TEX (HW_TEX * CCH)          // 786432 per-sample flat texture (channels-last)
#define OH 128
#define OW 64
#define P_OUT (OH * OW)               // 8192
#define M_OUT (P_OUT * CCH)           // 24576 rows per sample (channels-last)
#define NNZ 98304
#define OUT_ELEMS (BATCH * M_OUT)     // 786432

#define TB 1024
#define NROUND 4

// ---- R14 geometry: NCH=2 (idx read 2x instead of 4x), NE=16 ---------------
// Model (R6..R13 ledger): scan time ~ per-CU L1-miss line-requests at
// ~0.13 lines/cy (32 MSHR / ~250cy L2 latency); waves, codegen, and DMA path
// all proven non-levers. Requests/CU: R6 = 9216 idx + 12288 gather;
// NCH=2 cuts idx replication to 4608 -> predicted scan 56-66us.
#define NCH2 2
#define RPCH2 (M_OUT / NCH2)           // 12288 rows -> 48 KB LDS acc (static ok)
#define NE2 16
#define SEGE2 (NNZ / NE2)              // 6144 nnz per block-round
#define EPT2 6                         // nnz per thread per round
#define WS_NEED2 ((size_t)BATCH * NCH2 * NE2 * RPCH2 * 4)   // 50.33 MB

// ---- R6 fallback geometry (proven 72us) ------------------------------------
#define NCH 4
#define RPCH (M_OUT / NCH)             // 6144 rows -> 24 KB LDS
#define NE 8
#define SEGE (NNZ / NE)                // 12288
#define EPT 12
#define WS_NEED ((size_t)BATCH * NCH * NE * RPCH * 4)       // 25.17 MB

// ---------- R14 scan: 2-chunk, 16-seg, XCD-sample-phased --------------------
// blk: xcd = blk&7, slot = blk>>3 in [0,32) -> c = slot&1, e = slot>>1.
// Round rnd: all 32 blocks of an XCD scan sample s = rnd*8+xcd (L2-resident).
__global__ __launch_bounds__(TB) void scan2_kernel(
    const float* __restrict__ x,
    const int*   __restrict__ rows,
    const int*   __restrict__ cols,
    const float* __restrict__ vals,
    float* __restrict__ partial) {
    __shared__ __align__(16) float acc[RPCH2];     // 48 KB

    const int blk  = blockIdx.x;
    const int xcd  = blk & 7;
    const int slot = blk >> 3;
    const int c    = slot & (NCH2 - 1);
    const int e    = slot >> 1;
    const int t    = threadIdx.x;
    const int rbase = c * RPCH2;

    for (int rnd = 0; rnd < NROUND; ++rnd) {
        const int s = rnd * 8 + xcd;

        // zero 48 KB: 6 float2 per thread
        float2* acc2 = reinterpret_cast<float2*>(acc);
#pragma unroll
        for (int j = 0; j < RPCH2 / 2 / TB; ++j)
            acc2[t + j * TB] = make_float2(0.f, 0.f);
        __syncthreads();

        const size_t off = (size_t)s * NNZ + (size_t)e * SEGE2;
        const int2*   r2 = reinterpret_cast<const int2*>(rows + off);
        const int2*   c2 = reinterpret_cast<const int2*>(cols + off);
        const float2* v2 = reinterpret_cast<const float2*>(vals + off);
        const float*  xs = x + (size_t)s * N_TEX;

        // 3 x int2/float2 coalesced loads per stream = 6 nnz/thread
        int2 rr[3], cc[3]; float2 vv[3];
#pragma unroll
        for (int j = 0; j < 3; ++j) {
            rr[j] = r2[t + j * TB];
            cc[j] = c2[t + j * TB];
            vv[j] = v2[t + j * TB];
        }
        int ri[EPT2]; int ci[EPT2]; float vi[EPT2];
#pragma unroll
        for (int j = 0; j < 3; ++j) {
            ri[2 * j] = rr[j].x; ri[2 * j + 1] = rr[j].y;
            ci[2 * j] = cc[j].x; ci[2 * j + 1] = cc[j].y;
            vi[2 * j] = vv[j].x; vi[2 * j + 1] = vv[j].y;
        }

        // unconditional clamped gathers (OOR lanes -> xs[0] broadcast line;
        // proven equal to predicated in R6 vs R9/R10)
        float xv[EPT2];
#pragma unroll
        for (int i = 0; i < EPT2; ++i) {
            unsigned l = (unsigned)(ri[i] - rbase);
            int gi = (ci[i] % CCH) * HW_TEX + ci[i] / CCH;
            xv[i] = xs[(l < (unsigned)RPCH2) ? gi : 0];
        }

        // multiply + LDS atomic (exec-masked, no loads inside)
#pragma unroll
        for (int i = 0; i < EPT2; ++i) {
            unsigned l = (unsigned)(ri[i] - rbase);
            if (l < (unsigned)RPCH2)
                atomicAdd(&acc[l], vi[i] * xv[i]);
        }
        __syncthreads();

        // dump 48 KB partial, coalesced float2
        float2* pp = reinterpret_cast<float2*>(
            partial + (((size_t)s * NCH2 + c) * NE2 + e) * RPCH2);
#pragma unroll
        for (int j = 0; j < RPCH2 / 2 / TB; ++j)
            pp[t + j * TB] = acc2[t + j * TB];
        __syncthreads();
    }
}

// ---------- R14 reduce: sum NE2 partials, CHW transform, mask ---------------
__global__ __launch_bounds__(256) void reduce2_kernel(
    const float* __restrict__ partial,
    const float* __restrict__ mask,
    float* __restrict__ out) {
    int tid = blockIdx.x * 256 + threadIdx.x;       // over OUT_ELEMS/4
    if (tid >= OUT_ELEMS / 4) return;
    int s    = tid / (M_OUT / 4);
    int rcl4 = (tid % (M_OUT / 4)) * 4;
    int c    = rcl4 / RPCH2;
    int lr4  = rcl4 % RPCH2;

    const float4* pp = reinterpret_cast<const float4*>(
        partial + (((size_t)s * NCH2 + c) * NE2) * RPCH2 + lr4);
    float4 sum = make_float4(0.f, 0.f, 0.f, 0.f);
#pragma unroll
    for (int e = 0; e < NE2; ++e) {
        float4 p = pp[(size_t)e * (RPCH2 / 4)];
        sum.x += p.x; sum.y += p.y; sum.z += p.z; sum.w += p.w;
    }
    float* ob = out + (size_t)s * M_OUT;
    ob[(rcl4 + 0) % CCH * P_OUT + (rcl4 + 0) / CCH] = sum.x;
    ob[(rcl4 + 1) % CCH * P_OUT + (rcl4 + 1) / CCH] = sum.y;
    ob[(rcl4 + 2) % CCH * P_OUT + (rcl4 + 2) / CCH] = sum.z;
    ob[(rcl4 + 3) % CCH * P_OUT + (rcl4 + 3) / CCH] = sum.w;
    reinterpret_cast<float4*>(out + OUT_ELEMS)[tid] =
        reinterpret_cast<const float4*>(mask)[tid];
}

// ---------- R6 scan (proven 72us): 4-chunk, 8-seg, mid fallback -------------
__global__ __launch_bounds__(TB) void scan_pred8_kernel(
    const float* __restrict__ x,
    const int*   __restrict__ rows,
    const int*   __restrict__ cols,
    const float* __restrict__ vals,
    float* __restrict__ partial) {
    __shared__ __align__(16) float acc[RPCH];

    const int blk  = blockIdx.x;
    const int xcd  = blk & 7;
    const int slot = blk >> 3;
    const int c    = slot & (NCH - 1);
    const int e    = slot >> 2;
    const int t    = threadIdx.x;
    const int rbase = c * RPCH;

    for (int rnd = 0; rnd < NROUND; ++rnd) {
        const int s = rnd * 8 + xcd;
        float2* acc2 = reinterpret_cast<float2*>(acc);
#pragma unroll
        for (int j = 0; j < RPCH / 2 / TB; ++j)
            acc2[t + j * TB] = make_float2(0.f, 0.f);
        __syncthreads();

        const size_t off = (size_t)s * NNZ + (size_t)e * SEGE;
        const int4*   r4 = reinterpret_cast<const int4*>(rows + off);
        const int4*   c4 = reinterpret_cast<const int4*>(cols + off);
        const float4* v4 = reinterpret_cast<const float4*>(vals + off);
        const float*  xs = x + (size_t)s * N_TEX;

        int4 r[3], cc[3]; float4 v[3];
#pragma unroll
        for (int j = 0; j < 3; ++j) {
            r[j]  = r4[j * TB + t];
            cc[j] = c4[j * TB + t];
            v[j]  = v4[j * TB + t];
        }
#pragma unroll
        for (int j = 0; j < 3; ++j) {
            int   ri[4] = {r[j].x, r[j].y, r[j].z, r[j].w};
            int   ci[4] = {cc[j].x, cc[j].y, cc[j].z, cc[j].w};
            float vi[4] = {v[j].x, v[j].y, v[j].z, v[j].w};
#pragma unroll
            for (int k = 0; k < 4; ++k) {
                unsigned lr = (unsigned)(ri[k] - rbase);
                if (lr < (unsigned)RPCH) {
                    int gi = (ci[k] % CCH) * HW_TEX + ci[k] / CCH;
                    atomicAdd(&acc[lr], vi[k] * xs[gi]);
                }
            }
        }
        __syncthreads();

        float2* pp = reinterpret_cast<float2*>(
            partial + (((size_t)s * NCH + c) * NE + e) * RPCH);
#pragma unroll
        for (int j = 0; j < RPCH / 2 / TB; ++j)
            pp[t + j * TB] = acc2[t + j * TB];
        __syncthreads();
    }
}

__global__ __launch_bounds__(256) void reduce_chunk_kernel(
    const float* __restrict__ partial,
    const float* __restrict__ mask,
    float* __restrict__ out) {
    int tid = blockIdx.x * 256 + threadIdx.x;
    if (tid >= OUT_ELEMS / 4) return;
    int s    = tid / (M_OUT / 4);
    int rcl4 = (tid % (M_OUT / 4)) * 4;
    int c    = rcl4 / RPCH;
    int lr4  = rcl4 % RPCH;

    const float4* pp = reinterpret_cast<const float4*>(
        partial + (((size_t)s * NCH + c) * NE) * RPCH + lr4);
    float4 sum = make_float4(0.f, 0.f, 0.f, 0.f);
#pragma unroll
    for (int e = 0; e < NE; ++e) {
        float4 p = pp[(size_t)e * (RPCH / 4)];
        sum.x += p.x; sum.y += p.y; sum.z += p.z; sum.w += p.w;
    }
    float* ob = out + (size_t)s * M_OUT;
    ob[(rcl4 + 0) % CCH * P_OUT + (rcl4 + 0) / CCH] = sum.x;
    ob[(rcl4 + 1) % CCH * P_OUT + (rcl4 + 1) / CCH] = sum.y;
    ob[(rcl4 + 2) % CCH * P_OUT + (rcl4 + 2) / CCH] = sum.z;
    ob[(rcl4 + 3) % CCH * P_OUT + (rcl4 + 3) / CCH] = sum.w;
    reinterpret_cast<float4*>(out + OUT_ELEMS)[tid] =
        reinterpret_cast<const float4*>(mask)[tid];
}

// ---------- fallback (R2): no workspace needed ------------------------------
#define CHUNKS 8
#define RPC (M_OUT / CHUNKS)
#define BLOCK 1024
__global__ __launch_bounds__(BLOCK) void spmm_chunk_kernel(
    const float* __restrict__ x,
    const int*   __restrict__ rows,
    const int*   __restrict__ cols,
    const float* __restrict__ vals,
    const float* __restrict__ mask,
    float* __restrict__ out) {
    __shared__ float acc[RPC];
    const int blk = blockIdx.x;
    const int s   = blk / CHUNKS;
    const int c   = blk % CHUNKS;
    const int t   = threadIdx.x;
    const int rbase = c * RPC;
#pragma unroll
    for (int j = 0; j < RPC / BLOCK; ++j) acc[t + j * BLOCK] = 0.0f;
    __syncthreads();
    const int*   rs = rows + (size_t)s * NNZ;
    const int*   cs = cols + (size_t)s * NNZ;
    const float* vs = vals + (size_t)s * NNZ;
    const float* xs = x    + (size_t)s * N_TEX;
#pragma unroll 4
    for (int i = t; i < NNZ; i += BLOCK) {
        int r = rs[i];
        unsigned lr = (unsigned)(r - rbase);
        if (lr < (unsigned)RPC) {
            int   col = cs[i];
            float v   = vs[i];
            atomicAdd(&acc[lr], v * xs[(col % CCH) * HW_TEX + col / CCH]);
        }
    }
    __syncthreads();
    const size_t outbase = (size_t)s * M_OUT;
#pragma unroll
    for (int ch = 0; ch < CCH; ++ch)
        out[outbase + (size_t)ch * P_OUT + c * (P_OUT / CHUNKS) + t] = acc[t * CCH + ch];
    {
        float* mout = out + OUT_ELEMS;
        const int base = blk * RPC;
#pragma unroll
        for (int j = 0; j < RPC / BLOCK; ++j)
            mout[base + j * BLOCK + t] = mask[base + j * BLOCK + t];
    }
}

extern "C" void kernel_launch(void* const* d_in, const int* in_sizes, int n_in,
                              void* d_out, int out_size, void* d_ws, size_t ws_size,
                              hipStream_t stream) {
    const float* x    = (const float*)d_in[0];
    const int*   rows = (const int*)  d_in[1];
    const int*   cols = (const int*)  d_in[2];
    const float* vals = (const float*)d_in[3];
    const float* mask = (const float*)d_in[4];
    float* out = (float*)d_out;
    int rgrid = (OUT_ELEMS / 4 + 255) / 256;   // 768

    if (ws_size >= WS_NEED2) {
        float* partial = (float*)d_ws;
        scan2_kernel<<<256, TB, 0, stream>>>(x, rows, cols, vals, partial);
        reduce2_kernel<<<rgrid, 256, 0, stream>>>(partial, mask, out);
    } else if (ws_size >= WS_NEED) {
        float* partial = (float*)d_ws;
        scan_pred8_kernel<<<256, TB, 0, stream>>>(x, rows, cols, vals, partial);
        reduce_chunk_kernel<<<rgrid, 256, 0, stream>>>(partial, mask, out);
    } else {
        spmm_chunk_kernel<<<BATCH * CHUNKS, BLOCK, 0, stream>>>(x, rows, cols, vals, mask, out);
    }
}